// Round 1
// baseline (5120.842 us; speedup 1.0000x reference)
//
#include <hip/hip_runtime.h>
#include <hip/hip_bf16.h>

#define DI 12
#define DH 512
#define DT 256
#define DB 256

typedef float f32x4 __attribute__((ext_vector_type(4)));
typedef __bf16 bf16x8 __attribute__((ext_vector_type(8)));

__device__ __forceinline__ float sigm(float x) { return 1.f / (1.f + __expf(-x)); }
__device__ __forceinline__ float tanh_f(float x) {
    float xc = fminf(fmaxf(x, -15.f), 15.f);
    float e = __expf(-2.f * xc);
    return (1.f - e) / (1.f + e);
}
__device__ __forceinline__ float lrelu(float x) { return x > 0.f ? x : 0.01f * x; }
__device__ __forceinline__ unsigned short f2bf(float f) {
    return __builtin_bit_cast(unsigned short, (__bf16)f);
}

// ---------------- init: zero barrier counters ----------------
__global__ void init_kernel(unsigned* ctrE, unsigned* ctrD) {
    int i = blockIdx.x * 256 + threadIdx.x;
    if (i < 256) ctrE[i] = 0u;
    else ctrD[i - 256] = 0u;
}

// ---------------- encoder: persistent GRU ----------------
// grid 256 = 8 batch groups (32 rows) x 32 unit slices (16 units). 384 thr = 6 waves.
__global__ __launch_bounds__(384, 2)
void enc_kernel(const float* __restrict__ x, const float* __restrict__ w_ih,
                const float* __restrict__ w_hh, const float* __restrict__ b_ih,
                const float* __restrict__ b_hh, unsigned* __restrict__ hpp,
                float* __restrict__ hencF, unsigned* __restrict__ ctr)
{
    const int tid = threadIdx.x;
    const int bid = blockIdx.x;
    const int bg = bid & 7;          // batch group -> XCD under round-robin
    const int cb = bid >> 3;         // unit slice
    const int growbase = bg * 32;
    const int ub = cb * 16;
    const int wave = tid >> 6, lane = tid & 63;
    const int rt = wave / 3, g = wave % 3;   // row-tile, gate
    const int lrow = lane & 15, lk = lane >> 4;

    __shared__ unsigned short hbuf[32 * DH];   // bf16, XOR-swizzled
    __shared__ float xbuf[32][DI];
    __shared__ float gibuf[32][48];
    __shared__ float wih_s[48][DI];
    __shared__ float bih_s[48], bhh_s[48];
    __shared__ float RZ[2][2][16][16];
    __shared__ float hloc[32][16];

    for (int i = tid; i < 48 * DI; i += 384) {
        int c = i / DI, k = i % DI;
        int grow = (c >> 4) * DH + ub + (c & 15);
        wih_s[c][k] = w_ih[grow * DI + k];
    }
    if (tid < 48) {
        int grow = (tid >> 4) * DH + ub + (tid & 15);
        bih_s[tid] = b_ih[grow];
        bhh_s[tid] = b_hh[grow];
    }
    for (int i = tid; i < 512; i += 384) hloc[i >> 4][i & 15] = 0.f;
    for (int i = tid; i < 32 * DH / 2; i += 384) ((unsigned*)hbuf)[i] = 0u;  // h0 = 0

    // B fragments: W_hh slice, register-resident for the whole sequence.
    bf16x8 bfr[16];
    {
        const float* wr = w_hh + (size_t)(g * DH + ub + lrow) * DH;
        #pragma unroll
        for (int kk = 0; kk < 16; ++kk) {
            const float* p = wr + kk * 32 + lk * 8;
            bf16x8 v;
            #pragma unroll
            for (int j = 0; j < 8; ++j) v[j] = (__bf16)p[j];
            bfr[kk] = v;
        }
    }
    __syncthreads();

    unsigned gen = 0;
    for (int t = 0; t < DT; ++t) {
        { // x_t -> LDS (exactly one element per thread)
            int r = tid / DI, c = tid % DI;
            xbuf[r][c] = x[(size_t)(growbase + r) * (DT * DI) + (size_t)t * DI + c];
        }
        __syncthreads();
        { // gi = x_t @ w_ih_slice^T + b_ih  (scalar, K=12)
            int r = tid / 12, c0 = (tid % 12) * 4;
            float xr[DI];
            #pragma unroll
            for (int k = 0; k < DI; ++k) xr[k] = xbuf[r][k];
            #pragma unroll
            for (int q = 0; q < 4; ++q) {
                int c = c0 + q;
                float acc = bih_s[c];
                #pragma unroll
                for (int k = 0; k < DI; ++k) acc += xr[k] * wih_s[c][k];
                gibuf[r][c] = acc;
            }
        }
        __syncthreads();
        // gh = h @ w_hh_slice^T via MFMA
        f32x4 acc = {0.f, 0.f, 0.f, 0.f};
        {
            const int arow = rt * 16 + lrow;
            const unsigned rbase = (unsigned)arow * 1024u;
            const unsigned swz = (unsigned)((arow & 7) << 4);
            const char* hb = (const char*)hbuf;
            #pragma unroll
            for (int kk = 0; kk < 16; ++kk) {
                unsigned off = rbase + (((unsigned)(kk * 64 + lk * 16)) ^ swz);
                bf16x8 a = *(const bf16x8*)(hb + off);
                acc = __builtin_amdgcn_mfma_f32_16x16x32_bf16(a, bfr[kk], acc, 0, 0, 0);
            }
        }
        float hn[4];
        {
            int u = lrow;
            if (g == 0) {
                #pragma unroll
                for (int i = 0; i < 4; ++i) {
                    int row = rt * 16 + lk * 4 + i;
                    RZ[0][rt][lk * 4 + i][u] = sigm(acc[i] + bhh_s[u] + gibuf[row][u]);
                }
            } else if (g == 1) {
                #pragma unroll
                for (int i = 0; i < 4; ++i) {
                    int row = rt * 16 + lk * 4 + i;
                    RZ[1][rt][lk * 4 + i][u] = sigm(acc[i] + bhh_s[16 + u] + gibuf[row][16 + u]);
                }
            } else {
                #pragma unroll
                for (int i = 0; i < 4; ++i) hn[i] = acc[i] + bhh_s[32 + u];
            }
        }
        __syncthreads();
        if (g == 2) { // n gate + state update (fp32 state in hloc)
            int u = lrow;
            #pragma unroll
            for (int i = 0; i < 4; ++i) {
                int ri = lk * 4 + i;
                int row = rt * 16 + ri;
                float r = RZ[0][rt][ri][u];
                float z = RZ[1][rt][ri][u];
                float n = tanh_f(gibuf[row][32 + u] + r * hn[i]);
                hloc[row][u] = (1.f - z) * n + z * hloc[row][u];
            }
        }
        __syncthreads();
        bool last = (t == DT - 1);
        if (!last) {
            // publish h slice (bf16, agent-coherent) to ping-pong buffer
            unsigned* dst = hpp + ((t + 1) & 1) * (DB * DH / 2);
            if (tid < 256) {
                int row = tid >> 3, dc = tid & 7;
                unsigned val = (unsigned)f2bf(hloc[row][dc * 2]) |
                               ((unsigned)f2bf(hloc[row][dc * 2 + 1]) << 16);
                unsigned idx = (unsigned)(growbase + row) * (DH / 2) + (unsigned)(ub / 2) + dc;
                __hip_atomic_store(dst + idx, val, __ATOMIC_RELAXED, __HIP_MEMORY_SCOPE_AGENT);
            }
            __syncthreads();
            ++gen;
            if (tid == 0) {
                __hip_atomic_fetch_add(ctr + bg * 32, 1u, __ATOMIC_RELEASE, __HIP_MEMORY_SCOPE_AGENT);
                unsigned tgt = 32u * gen;
                while (__hip_atomic_load(ctr + bg * 32, __ATOMIC_ACQUIRE, __HIP_MEMORY_SCOPE_AGENT) < tgt)
                    __builtin_amdgcn_s_sleep(2);
            }
            __syncthreads();
            // stage full h rows for next step (qword coherent loads -> swizzled LDS)
            const unsigned long long* src =
                (const unsigned long long*)(hpp + ((t + 1) & 1) * (DB * DH / 2));
            for (int i = tid; i < 32 * DH / 4; i += 384) {
                int row = i >> 7, dq = i & 127;
                unsigned long long v = __hip_atomic_load(
                    src + (size_t)(growbase + row) * (DH / 4) + dq,
                    __ATOMIC_RELAXED, __HIP_MEMORY_SCOPE_AGENT);
                unsigned off = (unsigned)row * 1024u + (((unsigned)(dq * 8)) ^ ((unsigned)((row & 7) << 4)));
                *(unsigned long long*)((char*)hbuf + off) = v;
            }
            __syncthreads();
        } else {
            for (int i = tid; i < 512; i += 384) {
                int row = i >> 4, u = i & 15;
                hencF[(size_t)(growbase + row) * DH + ub + u] = hloc[row][u];
            }
        }
    }
}

// ---------------- latent head + decoder init ----------------
__global__ void mid_kernel(const float* __restrict__ henc, const float* __restrict__ eps,
                           const float* __restrict__ fc1_w, const float* __restrict__ fc1_b,
                           const float* __restrict__ fc11_w, const float* __restrict__ fc11_b,
                           const float* __restrict__ fc12_w, const float* __restrict__ fc12_b,
                           const float* __restrict__ fc2_w, const float* __restrict__ fc2_b,
                           const float* __restrict__ fc3_w, const float* __restrict__ fc3_b,
                           float* __restrict__ hdecF, unsigned* __restrict__ hppD0,
                           float* __restrict__ out)
{
    const int row = blockIdx.x, tid = threadIdx.x;  // 256 threads
    __shared__ float v0[512], v1[256], zb[64], ubuf[256];
    for (int k = tid; k < 512; k += 256) v0[k] = lrelu(henc[(size_t)row * 512 + k]);
    __syncthreads();
    {
        float a = fc1_b[tid];
        const float* w = fc1_w + (size_t)tid * 512;
        for (int k = 0; k < 512; k += 4) {
            float4 wv = *(const float4*)(w + k);
            a += wv.x * v0[k] + wv.y * v0[k + 1] + wv.z * v0[k + 2] + wv.w * v0[k + 3];
        }
        v1[tid] = lrelu(a);
    }
    __syncthreads();
    if (tid < 64) {
        float m = fc11_b[tid], lv = fc12_b[tid];
        const float* w1 = fc11_w + (size_t)tid * 256;
        const float* w2 = fc12_w + (size_t)tid * 256;
        for (int k = 0; k < 256; k += 4) {
            float4 a = *(const float4*)(w1 + k);
            float4 b = *(const float4*)(w2 + k);
            m  += a.x * v1[k] + a.y * v1[k + 1] + a.z * v1[k + 2] + a.w * v1[k + 3];
            lv += b.x * v1[k] + b.y * v1[k + 1] + b.z * v1[k + 2] + b.w * v1[k + 3];
        }
        out[786432 + row * 64 + tid] = m;
        out[802816 + row * 64 + tid] = lv;
        zb[tid] = m + __expf(0.5f * lv) * eps[row * 64 + tid];
    }
    __syncthreads();
    {
        float a = fc2_b[tid];
        const float* w = fc2_w + (size_t)tid * 64;
        for (int k = 0; k < 64; k += 4) {
            float4 wv = *(const float4*)(w + k);
            a += wv.x * zb[k] + wv.y * zb[k + 1] + wv.z * zb[k + 2] + wv.w * zb[k + 3];
        }
        ubuf[tid] = lrelu(a);
    }
    __syncthreads();
    {
        float hv[2];
        #pragma unroll
        for (int q = 0; q < 2; ++q) {
            int j = 2 * tid + q;
            float a = fc3_b[j];
            const float* w = fc3_w + (size_t)j * 256;
            for (int k = 0; k < 256; k += 4) {
                float4 wv = *(const float4*)(w + k);
                a += wv.x * ubuf[k] + wv.y * ubuf[k + 1] + wv.z * ubuf[k + 2] + wv.w * ubuf[k + 3];
            }
            hdecF[(size_t)row * 512 + j] = a;
            hv[q] = a;
        }
        hppD0[row * 256 + tid] = (unsigned)f2bf(hv[0]) | ((unsigned)f2bf(hv[1]) << 16);
    }
}

// ---------------- decoder: persistent autoregressive GRU ----------------
__global__ __launch_bounds__(384, 2)
void dec_kernel(const float* __restrict__ w_ih, const float* __restrict__ w_hh,
                const float* __restrict__ b_ih, const float* __restrict__ b_hh,
                const float* __restrict__ fc4_w, const float* __restrict__ fc4_b,
                const float* __restrict__ hdecF, unsigned* __restrict__ hpp,
                unsigned* __restrict__ ctr, float* __restrict__ out)
{
    const int tid = threadIdx.x;
    const int bid = blockIdx.x;
    const int bg = bid & 7;
    const int cb = bid >> 3;
    const int growbase = bg * 32;
    const int ub = cb * 16;
    const int wave = tid >> 6, lane = tid & 63;
    const int rt = wave / 3, g = wave % 3;
    const int lrow = lane & 15, lk = lane >> 4;

    __shared__ unsigned short hbuf[32 * DH];
    __shared__ float ybuf[32][DI];
    __shared__ float gibuf[32][48];
    __shared__ float wih_s[48][DI];
    __shared__ float bih_s[48], bhh_s[48];
    __shared__ float fb4[DI];
    __shared__ float RZ[2][2][16][16];
    __shared__ float hloc[32][16];

    for (int i = tid; i < 48 * DI; i += 384) {
        int c = i / DI, k = i % DI;
        int grow = (c >> 4) * DH + ub + (c & 15);
        wih_s[c][k] = w_ih[grow * DI + k];
    }
    if (tid < 48) {
        int grow = (tid >> 4) * DH + ub + (tid & 15);
        bih_s[tid] = b_ih[grow];
        bhh_s[tid] = b_hh[grow];
    }
    if (tid < DI) fb4[tid] = fc4_b[tid];
    for (int i = tid; i < 512; i += 384) {
        int row = i >> 4, u = i & 15;
        hloc[row][u] = hdecF[(size_t)(growbase + row) * DH + ub + u];
    }

    bf16x8 bfr[16];
    {
        const float* wr = w_hh + (size_t)(g * DH + ub + lrow) * DH;
        #pragma unroll
        for (int kk = 0; kk < 16; ++kk) {
            const float* p = wr + kk * 32 + lk * 8;
            bf16x8 v;
            #pragma unroll
            for (int j = 0; j < 8; ++j) v[j] = (__bf16)p[j];
            bfr[kk] = v;
        }
    }
    bf16x8 yfr[16];   // fc4 fragments (only meaningful on g==0 waves)
    {
        #pragma unroll
        for (int kk = 0; kk < 16; ++kk) {
            bf16x8 v;
            if (g == 0 && lrow < DI) {
                const float* p = fc4_w + (size_t)lrow * DH + kk * 32 + lk * 8;
                #pragma unroll
                for (int j = 0; j < 8; ++j) v[j] = (__bf16)p[j];
            } else {
                #pragma unroll
                for (int j = 0; j < 8; ++j) v[j] = (__bf16)0.f;
            }
            yfr[kk] = v;
        }
    }
    // prologue: stage h_dec rows
    {
        const unsigned long long* src = (const unsigned long long*)hpp;
        for (int i = tid; i < 32 * DH / 4; i += 384) {
            int row = i >> 7, dq = i & 127;
            unsigned long long v = __hip_atomic_load(
                src + (size_t)(growbase + row) * (DH / 4) + dq,
                __ATOMIC_RELAXED, __HIP_MEMORY_SCOPE_AGENT);
            unsigned off = (unsigned)row * 1024u + (((unsigned)(dq * 8)) ^ ((unsigned)((row & 7) << 4)));
            *(unsigned long long*)((char*)hbuf + off) = v;
        }
    }
    __syncthreads();

    unsigned gen = 0;
    for (int t = 0; t < DT; ++t) {
        // y_{t-1} = fc4(h_{t-1}) via MFMA on g==0 waves (t==0: y = 0)
        if (t == 0) {
            int r = tid / DI, c = tid % DI;
            ybuf[r][c] = 0.f;
        } else if (g == 0) {
            f32x4 ya = {0.f, 0.f, 0.f, 0.f};
            const int arow = rt * 16 + lrow;
            const unsigned rbase = (unsigned)arow * 1024u;
            const unsigned swz = (unsigned)((arow & 7) << 4);
            const char* hb = (const char*)hbuf;
            #pragma unroll
            for (int kk = 0; kk < 16; ++kk) {
                unsigned off = rbase + (((unsigned)(kk * 64 + lk * 16)) ^ swz);
                bf16x8 a = *(const bf16x8*)(hb + off);
                ya = __builtin_amdgcn_mfma_f32_16x16x32_bf16(a, yfr[kk], ya, 0, 0, 0);
            }
            if (lrow < DI) {
                #pragma unroll
                for (int i = 0; i < 4; ++i)
                    ybuf[rt * 16 + lk * 4 + i][lrow] = ya[i] + fb4[lrow];
            }
        }
        __syncthreads();
        { // gi from y_{t-1}
            int r = tid / 12, c0 = (tid % 12) * 4;
            float xr[DI];
            #pragma unroll
            for (int k = 0; k < DI; ++k) xr[k] = ybuf[r][k];
            #pragma unroll
            for (int q = 0; q < 4; ++q) {
                int c = c0 + q;
                float acc = bih_s[c];
                #pragma unroll
                for (int k = 0; k < DI; ++k) acc += xr[k] * wih_s[c][k];
                gibuf[r][c] = acc;
            }
        }
        if (cb == 0 && t > 0) { // y_{t-1} is output element t-1
            int r = tid / 12, c = tid % 12;
            out[(size_t)(growbase + r) * (DT * DI) + (size_t)(t - 1) * DI + c] = ybuf[r][c];
        }
        __syncthreads();
        f32x4 acc = {0.f, 0.f, 0.f, 0.f};
        {
            const int arow = rt * 16 + lrow;
            const unsigned rbase = (unsigned)arow * 1024u;
            const unsigned swz = (unsigned)((arow & 7) << 4);
            const char* hb = (const char*)hbuf;
            #pragma unroll
            for (int kk = 0; kk < 16; ++kk) {
                unsigned off = rbase + (((unsigned)(kk * 64 + lk * 16)) ^ swz);
                bf16x8 a = *(const bf16x8*)(hb + off);
                acc = __builtin_amdgcn_mfma_f32_16x16x32_bf16(a, bfr[kk], acc, 0, 0, 0);
            }
        }
        float hn[4];
        {
            int u = lrow;
            if (g == 0) {
                #pragma unroll
                for (int i = 0; i < 4; ++i) {
                    int row = rt * 16 + lk * 4 + i;
                    RZ[0][rt][lk * 4 + i][u] = sigm(acc[i] + bhh_s[u] + gibuf[row][u]);
                }
            } else if (g == 1) {
                #pragma unroll
                for (int i = 0; i < 4; ++i) {
                    int row = rt * 16 + lk * 4 + i;
                    RZ[1][rt][lk * 4 + i][u] = sigm(acc[i] + bhh_s[16 + u] + gibuf[row][16 + u]);
                }
            } else {
                #pragma unroll
                for (int i = 0; i < 4; ++i) hn[i] = acc[i] + bhh_s[32 + u];
            }
        }
        __syncthreads();
        if (g == 2) {
            int u = lrow;
            #pragma unroll
            for (int i = 0; i < 4; ++i) {
                int ri = lk * 4 + i;
                int row = rt * 16 + ri;
                float r = RZ[0][rt][ri][u];
                float z = RZ[1][rt][ri][u];
                float n = tanh_f(gibuf[row][32 + u] + r * hn[i]);
                hloc[row][u] = (1.f - z) * n + z * hloc[row][u];
            }
        }
        __syncthreads();
        {
            unsigned* dst = hpp + ((t + 1) & 1) * (DB * DH / 2);
            if (tid < 256) {
                int row = tid >> 3, dc = tid & 7;
                unsigned val = (unsigned)f2bf(hloc[row][dc * 2]) |
                               ((unsigned)f2bf(hloc[row][dc * 2 + 1]) << 16);
                unsigned idx = (unsigned)(growbase + row) * (DH / 2) + (unsigned)(ub / 2) + dc;
                __hip_atomic_store(dst + idx, val, __ATOMIC_RELAXED, __HIP_MEMORY_SCOPE_AGENT);
            }
            __syncthreads();
            ++gen;
            if (tid == 0) {
                __hip_atomic_fetch_add(ctr + bg * 32, 1u, __ATOMIC_RELEASE, __HIP_MEMORY_SCOPE_AGENT);
                unsigned tgt = 32u * gen;
                while (__hip_atomic_load(ctr + bg * 32, __ATOMIC_ACQUIRE, __HIP_MEMORY_SCOPE_AGENT) < tgt)
                    __builtin_amdgcn_s_sleep(2);
            }
            __syncthreads();
            const unsigned long long* src =
                (const unsigned long long*)(hpp + ((t + 1) & 1) * (DB * DH / 2));
            for (int i = tid; i < 32 * DH / 4; i += 384) {
                int row = i >> 7, dq = i & 127;
                unsigned long long v = __hip_atomic_load(
                    src + (size_t)(growbase + row) * (DH / 4) + dq,
                    __ATOMIC_RELAXED, __HIP_MEMORY_SCOPE_AGENT);
                unsigned off = (unsigned)row * 1024u + (((unsigned)(dq * 8)) ^ ((unsigned)((row & 7) << 4)));
                *(unsigned long long*)((char*)hbuf + off) = v;
            }
            __syncthreads();
        }
    }
    // epilogue: y_255 = fc4(h_255)
    if (g == 0) {
        f32x4 ya = {0.f, 0.f, 0.f, 0.f};
        const int arow = rt * 16 + lrow;
        const unsigned rbase = (unsigned)arow * 1024u;
        const unsigned swz = (unsigned)((arow & 7) << 4);
        const char* hb = (const char*)hbuf;
        #pragma unroll
        for (int kk = 0; kk < 16; ++kk) {
            unsigned off = rbase + (((unsigned)(kk * 64 + lk * 16)) ^ swz);
            bf16x8 a = *(const bf16x8*)(hb + off);
            ya = __builtin_amdgcn_mfma_f32_16x16x32_bf16(a, yfr[kk], ya, 0, 0, 0);
        }
        if (lrow < DI) {
            #pragma unroll
            for (int i = 0; i < 4; ++i)
                ybuf[rt * 16 + lk * 4 + i][lrow] = ya[i] + fb4[lrow];
        }
    }
    __syncthreads();
    if (cb == 0) {
        int r = tid / 12, c = tid % 12;
        out[(size_t)(growbase + r) * (DT * DI) + (size_t)(DT - 1) * DI + c] = ybuf[r][c];
    }
}

extern "C" void kernel_launch(void* const* d_in, const int* in_sizes, int n_in,
                              void* d_out, int out_size, void* d_ws, size_t ws_size,
                              hipStream_t stream)
{
    const float* x      = (const float*)d_in[0];
    const float* eps    = (const float*)d_in[1];
    const float* w_ih_e = (const float*)d_in[2];
    const float* w_hh_e = (const float*)d_in[3];
    const float* b_ih_e = (const float*)d_in[4];
    const float* b_hh_e = (const float*)d_in[5];
    const float* w_ih_d = (const float*)d_in[6];
    const float* w_hh_d = (const float*)d_in[7];
    const float* b_ih_d = (const float*)d_in[8];
    const float* b_hh_d = (const float*)d_in[9];
    const float* fc1_w  = (const float*)d_in[10];
    const float* fc1_b  = (const float*)d_in[11];
    const float* fc11_w = (const float*)d_in[12];
    const float* fc11_b = (const float*)d_in[13];
    const float* fc12_w = (const float*)d_in[14];
    const float* fc12_b = (const float*)d_in[15];
    const float* fc2_w  = (const float*)d_in[16];
    const float* fc2_b  = (const float*)d_in[17];
    const float* fc3_w  = (const float*)d_in[18];
    const float* fc3_b  = (const float*)d_in[19];
    const float* fc4_w  = (const float*)d_in[20];
    const float* fc4_b  = (const float*)d_in[21];

    char* ws = (char*)d_ws;
    unsigned* hppE = (unsigned*)(ws + 0);        // 2 x 256 x 512 bf16
    unsigned* hppD = (unsigned*)(ws + 524288);   // 2 x 256 x 512 bf16
    float* hencF   = (float*)(ws + 1048576);     // 256 x 512 f32
    float* hdecF   = (float*)(ws + 1572864);     // 256 x 512 f32
    unsigned* ctrE = (unsigned*)(ws + 2097152);  // 8 slots, 128B stride
    unsigned* ctrD = (unsigned*)(ws + 2098176);
    float* out = (float*)d_out;

    init_kernel<<<2, 256, 0, stream>>>(ctrE, ctrD);
    enc_kernel<<<256, 384, 0, stream>>>(x, w_ih_e, w_hh_e, b_ih_e, b_hh_e, hppE, hencF, ctrE);
    mid_kernel<<<256, 256, 0, stream>>>(hencF, eps, fc1_w, fc1_b, fc11_w, fc11_b,
                                        fc12_w, fc12_b, fc2_w, fc2_b, fc3_w, fc3_b,
                                        hdecF, hppD, out);
    dec_kernel<<<256, 384, 0, stream>>>(w_ih_d, w_hh_d, b_ih_d, b_hh_d, fc4_w, fc4_b,
                                        hdecF, hppD, ctrD, out);
}

// Round 5
// 3080.037 us; speedup vs baseline: 1.6626x; 1.6626x over previous
//
#include <hip/hip_runtime.h>
#include <hip/hip_bf16.h>

#define DI 12
#define DH 512
#define DT 256
#define DB 256
#define SCOPE __HIP_MEMORY_SCOPE_AGENT

typedef float f32x4 __attribute__((ext_vector_type(4)));
typedef __bf16 bf16x8 __attribute__((ext_vector_type(8)));

__device__ __forceinline__ float sigm(float x) { return 1.f / (1.f + __expf(-x)); }
__device__ __forceinline__ float tanh_f(float x) {
    float xc = fminf(fmaxf(x, -15.f), 15.f);
    float e = __expf(-2.f * xc);
    return (1.f - e) / (1.f + e);
}
__device__ __forceinline__ float lrelu(float x) { return x > 0.f ? x : 0.01f * x; }
__device__ __forceinline__ unsigned short f2bf(float f) {
    return __builtin_bit_cast(unsigned short, (__bf16)f);
}

// Parallel h staging: issue all L3 loads first (independent), then LDS-write.
__device__ __forceinline__ void stage_h(unsigned short* hbuf, const unsigned long long* src2, int tid) {
    unsigned long long tmp[11];
    #pragma unroll
    for (int j = 0; j < 11; ++j) {
        int i = tid + j * 384;
        if (i < 4096) tmp[j] = __hip_atomic_load(src2 + i, __ATOMIC_RELAXED, SCOPE);
    }
    #pragma unroll
    for (int j = 0; j < 11; ++j) {
        int i = tid + j * 384;
        if (i < 4096) {
            int row = i >> 7, dq = i & 127;
            unsigned off = (unsigned)row * 1024u + (((unsigned)(dq * 8)) ^ ((unsigned)((row & 7) << 4)));
            *(unsigned long long*)((char*)hbuf + off) = tmp[j];
        }
    }
}

// Flag barrier: wave 0 polls all 32 slice flags of its group (one coalesced load/iter).
__device__ __forceinline__ void barrier_wait(const unsigned* fl, int wave, int lane, unsigned gen) {
    if (wave == 0) {
        while (true) {
            unsigned v = __hip_atomic_load(fl + (lane & 31), __ATOMIC_RELAXED, SCOPE);
            if (__all((int)(v >= gen))) break;
            __builtin_amdgcn_s_sleep(1);
        }
        __builtin_amdgcn_fence(__ATOMIC_ACQUIRE, "agent");
    }
}

__device__ __forceinline__ f32x4 mfma_hbuf(const unsigned short* hbuf, const bf16x8* bw,
                                           int arow, int lk) {
    f32x4 acc = {0.f, 0.f, 0.f, 0.f};
    const unsigned rbase = (unsigned)arow * 1024u;
    const unsigned swz = (unsigned)((arow & 7) << 4);
    const char* hb = (const char*)hbuf;
    #pragma unroll
    for (int kk = 0; kk < 16; ++kk) {
        unsigned off = rbase + (((unsigned)(kk * 64 + lk * 16)) ^ swz);
        bf16x8 a = *(const bf16x8*)(hb + off);
        acc = __builtin_amdgcn_mfma_f32_16x16x32_bf16(a, bw[kk], acc, 0, 0, 0);
    }
    return acc;
}

// ---------------- init: zero generation flags ----------------
__global__ void init_kernel(unsigned* flE, unsigned* flD) {
    if (blockIdx.x == 0) flE[threadIdx.x] = 0u;
    else flD[threadIdx.x] = 0u;
}

// ---------------- encoder: persistent GRU ----------------
__global__ __launch_bounds__(384, 2)
void enc_kernel(const float* __restrict__ x, const float* __restrict__ w_ih,
                const float* __restrict__ w_hh, const float* __restrict__ b_ih,
                const float* __restrict__ b_hh, unsigned* __restrict__ hpp,
                float* __restrict__ hencF, unsigned* __restrict__ flags)
{
    const int tid = threadIdx.x;
    const int bid = blockIdx.x;
    const int bg = bid & 7;          // batch group
    const int cb = bid >> 3;         // unit slice
    const int growbase = bg * 32;
    const int ub = cb * 16;
    const int wave = tid >> 6, lane = tid & 63;
    const int rt = wave / 3, g = wave % 3;
    const int lrow = lane & 15, lk = lane >> 4;
    unsigned* flg = flags + bg * 32;

    __shared__ unsigned short hbuf[32 * DH];
    __shared__ float xbuf[32][DI];
    __shared__ float gibuf[32][48];
    __shared__ float wih_s[48][DI];
    __shared__ float bih_s[48], bhh_s[48];
    __shared__ float RZ[2][2][16][16];

    for (int i = tid; i < 48 * DI; i += 384) {
        int c = i / DI, k = i % DI;
        int grow = (c >> 4) * DH + ub + (c & 15);
        wih_s[c][k] = w_ih[grow * DI + k];
    }
    if (tid < 48) {
        int grow = (tid >> 4) * DH + ub + (tid & 15);
        bih_s[tid] = b_ih[grow];
        bhh_s[tid] = b_hh[grow];
    }
    for (int i = tid; i < 32 * DH / 2; i += 384) ((unsigned*)hbuf)[i] = 0u;  // h0 = 0
    { // x_0 -> LDS
        int r = tid / DI, c = tid % DI;
        xbuf[r][c] = x[(size_t)(growbase + r) * (DT * DI) + c];
    }

    bf16x8 bfr[16];  // W_hh slice, register-resident
    {
        const float* wr = w_hh + (size_t)(g * DH + ub + lrow) * DH;
        #pragma unroll
        for (int kk = 0; kk < 16; ++kk) {
            const float* p = wr + kk * 32 + lk * 8;
            bf16x8 v;
            #pragma unroll
            for (int j = 0; j < 8; ++j) v[j] = (__bf16)p[j];
            bfr[kk] = v;
        }
    }
    float hreg[4] = {0.f, 0.f, 0.f, 0.f};   // h state (g==2 waves)
    const int pid = (g != 2) ? ((rt * 2 + g) * 64 + lane) : 0;  // 0..255 for non-g2
    __syncthreads();

    for (int t = 0; t < DT; ++t) {
        const bool lastt = (t == DT - 1);
        // ---- A: gh MFMA + gi ----
        f32x4 acc = mfma_hbuf(hbuf, bfr, rt * 16 + lrow, lk);
        {
            int r = tid / 12, c0 = (tid % 12) * 4;
            float xr[DI];
            #pragma unroll
            for (int k = 0; k < DI; ++k) xr[k] = xbuf[r][k];
            #pragma unroll
            for (int q = 0; q < 4; ++q) {
                int c = c0 + q;
                float a2 = bih_s[c];
                #pragma unroll
                for (int k = 0; k < DI; ++k) a2 += xr[k] * wih_s[c][k];
                gibuf[r][c] = a2;
            }
        }
        __syncthreads();
        // ---- B: gates + x prefetch ----
        float hn[4];
        float xr0 = 0.f, xr1 = 0.f;
        {
            int u = lrow;
            if (g == 0) {
                #pragma unroll
                for (int i = 0; i < 4; ++i) {
                    int ri = lk * 4 + i;
                    RZ[0][rt][ri][u] = sigm(acc[i] + bhh_s[u] + gibuf[rt * 16 + ri][u]);
                }
            } else if (g == 1) {
                #pragma unroll
                for (int i = 0; i < 4; ++i) {
                    int ri = lk * 4 + i;
                    RZ[1][rt][ri][u] = sigm(acc[i] + bhh_s[16 + u] + gibuf[rt * 16 + ri][16 + u]);
                }
            } else {
                #pragma unroll
                for (int i = 0; i < 4; ++i) hn[i] = acc[i] + bhh_s[32 + u];
            }
        }
        if (g != 2 && !lastt) {
            xr0 = x[(size_t)(growbase + pid / 12) * (DT * DI) + (size_t)(t + 1) * DI + pid % 12];
            if (pid < 128) {
                int e = 256 + pid;
                xr1 = x[(size_t)(growbase + e / 12) * (DT * DI) + (size_t)(t + 1) * DI + e % 12];
            }
        }
        __syncthreads();
        // ---- C: combine (g2) + publish from registers ----
        if (g == 2) {
            int u = lrow;
            unsigned* dst = hpp + ((t + 1) & 1) * (DB * DH / 2);
            #pragma unroll
            for (int i = 0; i < 4; ++i) {
                int ri = lk * 4 + i;
                int row = rt * 16 + ri;
                float r = RZ[0][rt][ri][u];
                float z = RZ[1][rt][ri][u];
                float n = tanh_f(gibuf[row][32 + u] + r * hn[i]);
                hreg[i] = (1.f - z) * n + z * hreg[i];
                float hp = __shfl_xor(hreg[i], 1);
                if (!lastt) {
                    if (!(u & 1)) {
                        unsigned val = (unsigned)f2bf(hreg[i]) | ((unsigned)f2bf(hp) << 16);
                        __hip_atomic_store(dst + (unsigned)(growbase + row) * 256u +
                                           (unsigned)(cb * 8 + (u >> 1)),
                                           val, __ATOMIC_RELAXED, SCOPE);
                    }
                } else {
                    hencF[(size_t)(growbase + row) * DH + ub + u] = hreg[i];
                }
            }
        }
        if (lastt) break;
        __syncthreads();   // drains publish stores (implicit vmcnt(0) before s_barrier)
        const unsigned gen = (unsigned)(t + 1);
        if (tid == 0) __hip_atomic_store(flg + cb, gen, __ATOMIC_RELAXED, SCOPE);
        barrier_wait(flg, wave, lane, gen);
        __syncthreads();
        // ---- D: stage h_{t+1} + commit x prefetch ----
        stage_h(hbuf, (const unsigned long long*)(hpp + ((t + 1) & 1) * (DB * DH / 2)) +
                      (size_t)growbase * 128, tid);
        if (g != 2) {
            xbuf[pid / 12][pid % 12] = xr0;
            if (pid < 128) { int e = 256 + pid; xbuf[e / 12][e % 12] = xr1; }
        }
        __syncthreads();
    }
}

// ---------------- latent head + decoder init ----------------
__global__ void mid_kernel(const float* __restrict__ henc, const float* __restrict__ eps,
                           const float* __restrict__ fc1_w, const float* __restrict__ fc1_b,
                           const float* __restrict__ fc11_w, const float* __restrict__ fc11_b,
                           const float* __restrict__ fc12_w, const float* __restrict__ fc12_b,
                           const float* __restrict__ fc2_w, const float* __restrict__ fc2_b,
                           const float* __restrict__ fc3_w, const float* __restrict__ fc3_b,
                           float* __restrict__ hdecF, unsigned* __restrict__ hppD0,
                           float* __restrict__ out)
{
    const int row = blockIdx.x, tid = threadIdx.x;  // 256 threads
    __shared__ float v0[512], v1[256], zb[64], ubuf[256];
    for (int k = tid; k < 512; k += 256) v0[k] = lrelu(henc[(size_t)row * 512 + k]);
    __syncthreads();
    {
        float a = fc1_b[tid];
        const float* w = fc1_w + (size_t)tid * 512;
        for (int k = 0; k < 512; k += 4) {
            float4 wv = *(const float4*)(w + k);
            a += wv.x * v0[k] + wv.y * v0[k + 1] + wv.z * v0[k + 2] + wv.w * v0[k + 3];
        }
        v1[tid] = lrelu(a);
    }
    __syncthreads();
    if (tid < 64) {
        float m = fc11_b[tid], lv = fc12_b[tid];
        const float* w1 = fc11_w + (size_t)tid * 256;
        const float* w2 = fc12_w + (size_t)tid * 256;
        for (int k = 0; k < 256; k += 4) {
            float4 a = *(const float4*)(w1 + k);
            float4 b = *(const float4*)(w2 + k);
            m  += a.x * v1[k] + a.y * v1[k + 1] + a.z * v1[k + 2] + a.w * v1[k + 3];
            lv += b.x * v1[k] + b.y * v1[k + 1] + b.z * v1[k + 2] + b.w * v1[k + 3];
        }
        out[786432 + row * 64 + tid] = m;
        out[802816 + row * 64 + tid] = lv;
        zb[tid] = m + __expf(0.5f * lv) * eps[row * 64 + tid];
    }
    __syncthreads();
    {
        float a = fc2_b[tid];
        const float* w = fc2_w + (size_t)tid * 64;
        for (int k = 0; k < 64; k += 4) {
            float4 wv = *(const float4*)(w + k);
            a += wv.x * zb[k] + wv.y * zb[k + 1] + wv.z * zb[k + 2] + wv.w * zb[k + 3];
        }
        ubuf[tid] = lrelu(a);
    }
    __syncthreads();
    {
        float hv[2];
        #pragma unroll
        for (int q = 0; q < 2; ++q) {
            int j = 2 * tid + q;
            float a = fc3_b[j];
            const float* w = fc3_w + (size_t)j * 256;
            for (int k = 0; k < 256; k += 4) {
                float4 wv = *(const float4*)(w + k);
                a += wv.x * ubuf[k] + wv.y * ubuf[k + 1] + wv.z * ubuf[k + 2] + wv.w * ubuf[k + 3];
            }
            hdecF[(size_t)row * 512 + j] = a;
            hv[q] = a;
        }
        hppD0[row * 256 + tid] = (unsigned)f2bf(hv[0]) | ((unsigned)f2bf(hv[1]) << 16);
    }
}

// ---------------- decoder: persistent autoregressive GRU ----------------
__global__ __launch_bounds__(384, 2)
void dec_kernel(const float* __restrict__ w_ih, const float* __restrict__ w_hh,
                const float* __restrict__ b_ih, const float* __restrict__ b_hh,
                const float* __restrict__ fc4_w, const float* __restrict__ fc4_b,
                const float* __restrict__ hdecF, unsigned* __restrict__ hpp,
                unsigned* __restrict__ flags, float* __restrict__ out)
{
    const int tid = threadIdx.x;
    const int bid = blockIdx.x;
    const int bg = bid & 7;
    const int cb = bid >> 3;
    const int growbase = bg * 32;
    const int ub = cb * 16;
    const int wave = tid >> 6, lane = tid & 63;
    const int rt = wave / 3, g = wave % 3;
    const int lrow = lane & 15, lk = lane >> 4;
    unsigned* flg = flags + bg * 32;

    __shared__ unsigned short hbuf[32 * DH];
    __shared__ float ybuf[32][DI];
    __shared__ float gibuf[32][48];
    __shared__ float wih_s[48][DI];
    __shared__ float bih_s[48], bhh_s[48];
    __shared__ float fb4[DI];
    __shared__ float RZ[2][2][16][16];

    for (int i = tid; i < 48 * DI; i += 384) {
        int c = i / DI, k = i % DI;
        int grow = (c >> 4) * DH + ub + (c & 15);
        wih_s[c][k] = w_ih[grow * DI + k];
    }
    if (tid < 48) {
        int grow = (tid >> 4) * DH + ub + (tid & 15);
        bih_s[tid] = b_ih[grow];
        bhh_s[tid] = b_hh[grow];
    }
    if (tid < DI) fb4[tid] = fc4_b[tid];

    bf16x8 bfr[16];
    {
        const float* wr = w_hh + (size_t)(g * DH + ub + lrow) * DH;
        #pragma unroll
        for (int kk = 0; kk < 16; ++kk) {
            const float* p = wr + kk * 32 + lk * 8;
            bf16x8 v;
            #pragma unroll
            for (int j = 0; j < 8; ++j) v[j] = (__bf16)p[j];
            bfr[kk] = v;
        }
    }
    bf16x8 yfr[16];  // fc4 B-fragments (g==0 waves)
    {
        #pragma unroll
        for (int kk = 0; kk < 16; ++kk) {
            bf16x8 v;
            if (g == 0 && lrow < DI) {
                const float* p = fc4_w + (size_t)lrow * DH + kk * 32 + lk * 8;
                #pragma unroll
                for (int j = 0; j < 8; ++j) v[j] = (__bf16)p[j];
            } else {
                #pragma unroll
                for (int j = 0; j < 8; ++j) v[j] = (__bf16)0.f;
            }
            yfr[kk] = v;
        }
    }
    float hreg[4] = {0.f, 0.f, 0.f, 0.f};
    if (g == 2) {
        #pragma unroll
        for (int i = 0; i < 4; ++i)
            hreg[i] = hdecF[(size_t)(growbase + rt * 16 + lk * 4 + i) * DH + ub + lrow];
    }
    // prologue: stage h_dec
    stage_h(hbuf, (const unsigned long long*)hpp + (size_t)growbase * 128, tid);
    __syncthreads();

    for (int t = 0; t < DT; ++t) {
        // ---- Y: y_{t-1} = fc4(h_t) ----
        if (t == 0) {
            int r = tid / DI, c = tid % DI;
            ybuf[r][c] = 0.f;
        } else if (g == 0) {
            f32x4 ya = mfma_hbuf(hbuf, yfr, rt * 16 + lrow, lk);
            if (lrow < DI) {
                #pragma unroll
                for (int i = 0; i < 4; ++i)
                    ybuf[rt * 16 + lk * 4 + i][lrow] = ya[i] + fb4[lrow];
            }
        }
        __syncthreads();
        // ---- A: gh MFMA + gi + y output ----
        f32x4 acc = mfma_hbuf(hbuf, bfr, rt * 16 + lrow, lk);
        {
            int r = tid / 12, c0 = (tid % 12) * 4;
            float yr[DI];
            #pragma unroll
            for (int k = 0; k < DI; ++k) yr[k] = ybuf[r][k];
            #pragma unroll
            for (int q = 0; q < 4; ++q) {
                int c = c0 + q;
                float a2 = bih_s[c];
                #pragma unroll
                for (int k = 0; k < DI; ++k) a2 += yr[k] * wih_s[c][k];
                gibuf[r][c] = a2;
            }
        }
        if (cb == 0 && t > 0) {
            int r = tid / 12, c = tid % 12;
            out[(size_t)(growbase + r) * (DT * DI) + (size_t)(t - 1) * DI + c] = ybuf[r][c];
        }
        __syncthreads();
        // ---- B: gates ----
        float hn[4];
        {
            int u = lrow;
            if (g == 0) {
                #pragma unroll
                for (int i = 0; i < 4; ++i) {
                    int ri = lk * 4 + i;
                    RZ[0][rt][ri][u] = sigm(acc[i] + bhh_s[u] + gibuf[rt * 16 + ri][u]);
                }
            } else if (g == 1) {
                #pragma unroll
                for (int i = 0; i < 4; ++i) {
                    int ri = lk * 4 + i;
                    RZ[1][rt][ri][u] = sigm(acc[i] + bhh_s[16 + u] + gibuf[rt * 16 + ri][16 + u]);
                }
            } else {
                #pragma unroll
                for (int i = 0; i < 4; ++i) hn[i] = acc[i] + bhh_s[32 + u];
            }
        }
        __syncthreads();
        // ---- C: combine + publish (every step; epilogue needs h_256) ----
        if (g == 2) {
            int u = lrow;
            unsigned* dst = hpp + ((t + 1) & 1) * (DB * DH / 2);
            #pragma unroll
            for (int i = 0; i < 4; ++i) {
                int ri = lk * 4 + i;
                int row = rt * 16 + ri;
                float r = RZ[0][rt][ri][u];
                float z = RZ[1][rt][ri][u];
                float n = tanh_f(gibuf[row][32 + u] + r * hn[i]);
                hreg[i] = (1.f - z) * n + z * hreg[i];
                float hp = __shfl_xor(hreg[i], 1);
                if (!(u & 1)) {
                    unsigned val = (unsigned)f2bf(hreg[i]) | ((unsigned)f2bf(hp) << 16);
                    __hip_atomic_store(dst + (unsigned)(growbase + row) * 256u +
                                       (unsigned)(cb * 8 + (u >> 1)),
                                       val, __ATOMIC_RELAXED, SCOPE);
                }
            }
        }
        __syncthreads();   // drains publish stores
        const unsigned gen = (unsigned)(t + 1);
        if (tid == 0) __hip_atomic_store(flg + cb, gen, __ATOMIC_RELAXED, SCOPE);
        barrier_wait(flg, wave, lane, gen);
        __syncthreads();
        stage_h(hbuf, (const unsigned long long*)(hpp + ((t + 1) & 1) * (DB * DH / 2)) +
                      (size_t)growbase * 128, tid);
        __syncthreads();
    }
    // epilogue: y_255 = fc4(h_256)
    if (g == 0) {
        f32x4 ya = mfma_hbuf(hbuf, yfr, rt * 16 + lrow, lk);
        if (lrow < DI) {
            #pragma unroll
            for (int i = 0; i < 4; ++i)
                ybuf[rt * 16 + lk * 4 + i][lrow] = ya[i] + fb4[lrow];
        }
    }
    __syncthreads();
    if (cb == 0) {
        int r = tid / 12, c = tid % 12;
        out[(size_t)(growbase + r) * (DT * DI) + (size_t)(DT - 1) * DI + c] = ybuf[r][c];
    }
}

extern "C" void kernel_launch(void* const* d_in, const int* in_sizes, int n_in,
                              void* d_out, int out_size, void* d_ws, size_t ws_size,
                              hipStream_t stream)
{
    const float* x      = (const float*)d_in[0];
    const float* eps    = (const float*)d_in[1];
    const float* w_ih_e = (const float*)d_in[2];
    const float* w_hh_e = (const float*)d_in[3];
    const float* b_ih_e = (const float*)d_in[4];
    const float* b_hh_e = (const float*)d_in[5];
    const float* w_ih_d = (const float*)d_in[6];
    const float* w_hh_d = (const float*)d_in[7];
    const float* b_ih_d = (const float*)d_in[8];
    const float* b_hh_d = (const float*)d_in[9];
    const float* fc1_w  = (const float*)d_in[10];
    const float* fc1_b  = (const float*)d_in[11];
    const float* fc11_w = (const float*)d_in[12];
    const float* fc11_b = (const float*)d_in[13];
    const float* fc12_w = (const float*)d_in[14];
    const float* fc12_b = (const float*)d_in[15];
    const float* fc2_w  = (const float*)d_in[16];
    const float* fc2_b  = (const float*)d_in[17];
    const float* fc3_w  = (const float*)d_in[18];
    const float* fc3_b  = (const float*)d_in[19];
    const float* fc4_w  = (const float*)d_in[20];
    const float* fc4_b  = (const float*)d_in[21];

    char* ws = (char*)d_ws;
    unsigned* hppE  = (unsigned*)(ws + 0);        // 2 x 256 x 512 bf16
    unsigned* hppD  = (unsigned*)(ws + 524288);   // 2 x 256 x 512 bf16
    float* hencF    = (float*)(ws + 1048576);     // 256 x 512 f32
    float* hdecF    = (float*)(ws + 1572864);     // 256 x 512 f32
    unsigned* flagE = (unsigned*)(ws + 2097152);  // 8 groups x 32 slice flags
    unsigned* flagD = (unsigned*)(ws + 2098176);
    float* out = (float*)d_out;

    init_kernel<<<2, 256, 0, stream>>>(flagE, flagD);
    enc_kernel<<<256, 384, 0, stream>>>(x, w_ih_e, w_hh_e, b_ih_e, b_hh_e, hppE, hencF, flagE);
    mid_kernel<<<256, 256, 0, stream>>>(hencF, eps, fc1_w, fc1_b, fc11_w, fc11_b,
                                        fc12_w, fc12_b, fc2_w, fc2_b, fc3_w, fc3_b,
                                        hdecF, hppD, out);
    dec_kernel<<<256, 384, 0, stream>>>(w_ih_d, w_hh_d, b_ih_d, b_hh_d, fc4_w, fc4_b,
                                        hdecF, hppD, flagD, out);
}